// Round 4
// baseline (682.446 us; speedup 1.0000x reference)
//
#include <hip/hip_runtime.h>
#include <hip/hip_bf16.h>

#define N_NODES 200000
#define N_EDGES 6400000
#define K_BUCKETS 256
#define BUCKET 784          // 256*784 = 200704 >= 200000; dstLocal < 1024
#define NSB 1600            // scatter/hist blocks
#define CHUNK 4000          // NSB*CHUNK == N_EDGES exactly

// ---------------- fast path kernels ----------------

// x_out = z0 ; Scum = 0
__global__ __launch_bounds__(256) void prep_kernel(
    const float4* __restrict__ z0, float4* __restrict__ x_out,
    float* __restrict__ Scum)
{
    int n = blockIdx.x * 256 + threadIdx.x;
    if (n < N_NODES) { x_out[n] = z0[n]; Scum[n] = 0.0f; }
}

// per-chunk bucket histogram, transposed layout counts_T[k*NSB + sb]
__global__ __launch_bounds__(256) void hist_kernel(const int* __restrict__ dst,
                                                   int* __restrict__ counts_T)
{
    __shared__ int cnt[K_BUCKETS];
    int tid = threadIdx.x, sb = blockIdx.x;
    cnt[tid] = 0;
    __syncthreads();
    int e0 = sb * CHUNK;
    for (int i = tid; i < CHUNK; i += 256)
        atomicAdd(&cnt[dst[e0 + i] / BUCKET], 1);     // LDS atomic
    __syncthreads();
    counts_T[(size_t)tid * NSB + sb] = cnt[tid];
}

// per-bucket column scan: baseRel_T[k][sb] = exclusive prefix of counts_T[k][*],
// tot[k] = column sum. 256 blocks, contiguous columns.
__global__ __launch_bounds__(256) void scan_cols(const int* __restrict__ counts_T,
                                                 int* __restrict__ baseRel_T,
                                                 int* __restrict__ tot)
{
    __shared__ int buf[256];
    __shared__ int carry_s;
    int k = blockIdx.x, tid = threadIdx.x;
    if (tid == 0) carry_s = 0;
    __syncthreads();
    const int* col = counts_T + (size_t)k * NSB;
    int* outc = baseRel_T + (size_t)k * NSB;
    for (int base = 0; base < NSB; base += 256) {
        int idx = base + tid;
        int v = (idx < NSB) ? col[idx] : 0;
        buf[tid] = v;
        __syncthreads();
        for (int off = 1; off < 256; off <<= 1) {
            int t = (tid >= off) ? buf[tid - off] : 0;
            __syncthreads();
            buf[tid] += t;
            __syncthreads();
        }
        int incl = buf[tid];
        if (idx < NSB) outc[idx] = carry_s + incl - v;   // exclusive
        __syncthreads();
        if (tid == 255) carry_s += incl;
        __syncthreads();
    }
    if (tid == 255) tot[k] = carry_s;
}

// scan of 256 bucket totals -> bstart[0..256]
__global__ __launch_bounds__(256) void scan_tot(const int* __restrict__ tot,
                                                int* __restrict__ bstart)
{
    __shared__ int buf[256];
    int tid = threadIdx.x;
    int v = tot[tid];
    buf[tid] = v;
    __syncthreads();
    for (int off = 1; off < 256; off <<= 1) {
        int t = (tid >= off) ? buf[tid - off] : 0;
        __syncthreads();
        buf[tid] += t;
        __syncthreads();
    }
    bstart[tid] = buf[tid] - v;
    if (tid == 255) bstart[256] = buf[255];
}

// one pass over all edge inputs: bucketize, precompute per-layer c_i (bf16)
__global__ __launch_bounds__(256) void scatter_kernel(
    const int* __restrict__ src, const int* __restrict__ dst,
    const float* __restrict__ r, const float* __restrict__ r_hat,
    const float* __restrict__ W, const float* __restrict__ b,
    const int* __restrict__ baseRel_T, const int* __restrict__ bstart,
    int* __restrict__ packedA,
    __hip_bfloat16* __restrict__ c0a, __hip_bfloat16* __restrict__ c1a,
    __hip_bfloat16* __restrict__ c2a)
{
    __shared__ int cur[K_BUCKETS];
    int tid = threadIdx.x, sb = blockIdx.x;
    cur[tid] = bstart[tid] + baseRel_T[(size_t)tid * NSB + sb];
    __syncthreads();

    float w8_0 = W[8],  w9_0 = W[9],  w10_0 = W[10], w11_0 = W[11], b0 = b[0];
    float w8_1 = W[20], w9_1 = W[21], w10_1 = W[22], w11_1 = W[23], b1 = b[1];
    float w8_2 = W[32], w9_2 = W[33], w10_2 = W[34], w11_2 = W[35], b2 = b[2];

    int e0 = sb * CHUNK;
    for (int i = tid; i < CHUNK; i += 256) {
        int e = e0 + i;
        int d = dst[e];
        int k = d / BUCKET;
        int dl = d - k * BUCKET;
        int pos = atomicAdd(&cur[k], 1);                 // LDS atomic slot
        int s = src[e];
        float rv = r[e];
        size_t he = 3 * (size_t)e;
        float h0 = r_hat[he], h1 = r_hat[he + 1], h2 = r_hat[he + 2];
        packedA[pos] = (s << 10) | dl;
        c0a[pos] = __float2bfloat16(w8_0 * rv + w9_0 * h0 + w10_0 * h1 + w11_0 * h2 + b0);
        c1a[pos] = __float2bfloat16(w8_1 * rv + w9_1 * h0 + w10_1 * h1 + w11_1 * h2 + b1);
        c2a[pos] = __float2bfloat16(w8_2 * rv + w9_2 * h0 + w10_2 * h1 + w11_2 * h2 + b2);
    }
}

// per-node scalars for layer i: u = a.z0 + sum(a)*S ; v = b.z0 + sum(b)*S
__global__ __launch_bounds__(256) void uv_kernel(
    const float4* __restrict__ z0, const float* __restrict__ Scum,
    const float* __restrict__ Wl,
    float* __restrict__ u, float* __restrict__ v)
{
    int n = blockIdx.x * 256 + threadIdx.x;
    if (n >= N_NODES) return;
    float a0 = Wl[0], a1 = Wl[1], a2 = Wl[2], a3 = Wl[3];
    float q0 = Wl[4], q1 = Wl[5], q2 = Wl[6], q3 = Wl[7];
    float A = a0 + a1 + a2 + a3, B = q0 + q1 + q2 + q3;
    float4 zv = z0[n];
    float S = Scum[n];
    u[n] = a0 * zv.x + a1 * zv.y + a2 * zv.z + a3 * zv.w + A * S;
    v[n] = q0 * zv.x + q1 * zv.y + q2 * zv.z + q3 * zv.w + B * S;
}

// scalar SpMV layer: one block owns one bucket; LDS aggregation; no global atomics
__global__ __launch_bounds__(1024) void layer_kernel(
    const int* __restrict__ packedA, const __hip_bfloat16* __restrict__ cpl,
    const int* __restrict__ bstart,
    const float* __restrict__ u, const float* __restrict__ v,
    float* __restrict__ Scum, int final_layer,
    const float4* __restrict__ z0, float4* __restrict__ z_out)
{
    __shared__ float vsl[BUCKET];
    __shared__ float aggsl[BUCKET];
    int tid = threadIdx.x, k = blockIdx.x;
    int nbase = k * BUCKET;
    int nn = min(BUCKET, N_NODES - nbase);

    for (int i = tid; i < nn; i += 1024) { vsl[i] = v[nbase + i]; aggsl[i] = 0.0f; }
    __syncthreads();

    int estart = bstart[k], eend = bstart[k + 1];
    for (int j = estart + tid; j < eend; j += 1024) {
        int pack = packedA[j];
        int s = pack >> 10;
        int dl = pack & 1023;
        float t = u[s] + vsl[dl] + __bfloat162float(cpl[j]);
        atomicAdd(&aggsl[dl], t);                        // ds_add_f32
    }
    __syncthreads();

    for (int i = tid; i < nn; i += 1024) {
        float S = Scum[nbase + i] + aggsl[i];
        Scum[nbase + i] = S;
        if (final_layer) {
            float4 zv = z0[nbase + i];
            zv.x += S; zv.y += S; zv.z += S; zv.w += S;
            z_out[nbase + i] = zv;
        }
    }
}

// ---------------- fallback (round-2) kernels ----------------

__global__ __launch_bounds__(256) void init_kernel(
    const float4* __restrict__ z_in, float4* __restrict__ z_cur,
    float4* __restrict__ x_out, float* __restrict__ agg)
{
    int n = blockIdx.x * blockDim.x + threadIdx.x;
    if (n < N_NODES) {
        float4 vv = z_in[n];
        z_cur[n] = vv; x_out[n] = vv; agg[n] = 0.0f;
    }
}

__global__ __launch_bounds__(256) void edge_kernel(
    const float* __restrict__ z, const float* __restrict__ r,
    const float* __restrict__ r_hat, const int* __restrict__ src,
    const int* __restrict__ dst, const float* __restrict__ Wl,
    const float* __restrict__ bl, float* __restrict__ agg)
{
    int e = blockIdx.x * blockDim.x + threadIdx.x;
    if (e >= N_EDGES) return;
    float w0 = Wl[0], w1 = Wl[1], w2 = Wl[2], w3 = Wl[3];
    float w4 = Wl[4], w5 = Wl[5], w6 = Wl[6], w7 = Wl[7];
    float w8 = Wl[8], w9 = Wl[9], w10 = Wl[10], w11 = Wl[11];
    float bias = bl[0];
    int s = src[e], d = dst[e];
    float4 zs = ((const float4*)z)[s];
    float4 zd = ((const float4*)z)[d];
    float rv = r[e];
    const float* rh = r_hat + 3 * (size_t)e;
    float msg = w0*zs.x + w1*zs.y + w2*zs.z + w3*zs.w
              + w4*zd.x + w5*zd.y + w6*zd.z + w7*zd.w
              + w8*rv + w9*rh[0] + w10*rh[1] + w11*rh[2] + bias;
    unsafeAtomicAdd(&agg[d], msg);
}

__global__ __launch_bounds__(256) void node_update(float4* __restrict__ z_cur,
                                                   float* __restrict__ agg)
{
    int n = blockIdx.x * blockDim.x + threadIdx.x;
    if (n < N_NODES) {
        float a = agg[n]; float4 vv = z_cur[n];
        vv.x += a; vv.y += a; vv.z += a; vv.w += a;
        z_cur[n] = vv; agg[n] = 0.0f;
    }
}

__global__ __launch_bounds__(256) void final_update(const float4* __restrict__ z_cur,
                                                    const float* __restrict__ agg,
                                                    float4* __restrict__ z_out)
{
    int n = blockIdx.x * blockDim.x + threadIdx.x;
    if (n < N_NODES) {
        float a = agg[n]; float4 vv = z_cur[n];
        vv.x += a; vv.y += a; vv.z += a; vv.w += a;
        z_out[n] = vv;
    }
}

// ---------------- launch ----------------

extern "C" void kernel_launch(void* const* d_in, const int* in_sizes, int n_in,
                              void* d_out, int out_size, void* d_ws, size_t ws_size,
                              hipStream_t stream)
{
    const float* z     = (const float*)d_in[0];
    const float* r     = (const float*)d_in[1];
    const float* r_hat = (const float*)d_in[2];
    const float* W     = (const float*)d_in[3];
    const float* b     = (const float*)d_in[4];
    const int*   src   = (const int*)d_in[5];
    const int*   dst   = (const int*)d_in[6];
    float* out = (float*)d_out;

    // workspace layout (16B aligned blocks)
    char* ws = (char*)d_ws;
    size_t off = 0;
    int* packedA = (int*)(ws + off);            off += (size_t)N_EDGES * 4;
    __hip_bfloat16* c0a = (__hip_bfloat16*)(ws + off); off += (size_t)N_EDGES * 2;
    __hip_bfloat16* c1a = (__hip_bfloat16*)(ws + off); off += (size_t)N_EDGES * 2;
    __hip_bfloat16* c2a = (__hip_bfloat16*)(ws + off); off += (size_t)N_EDGES * 2;
    int* counts_T  = (int*)(ws + off);          off += (size_t)K_BUCKETS * NSB * 4;
    int* baseRel_T = (int*)(ws + off);          off += (size_t)K_BUCKETS * NSB * 4;
    int* tot    = (int*)(ws + off);             off += (size_t)K_BUCKETS * 4;
    int* bstart = (int*)(ws + off);             off += ((size_t)(K_BUCKETS + 1) * 4 + 12) & ~(size_t)15;
    float* Scum = (float*)(ws + off);           off += (size_t)N_NODES * 4;
    float* ubuf = (float*)(ws + off);           off += (size_t)N_NODES * 4;
    float* vbuf = (float*)(ws + off);           off += (size_t)N_NODES * 4;
    size_t required = off;

    dim3 nblk((N_NODES + 255) / 256);

    if (ws_size >= required) {
        // -------- fast path: scalar-SpMV decomposition --------
        prep_kernel<<<nblk, 256, 0, stream>>>(
            (const float4*)z, (float4*)(out + 4 * (size_t)N_NODES), Scum);
        hist_kernel<<<NSB, 256, 0, stream>>>(dst, counts_T);
        scan_cols<<<K_BUCKETS, 256, 0, stream>>>(counts_T, baseRel_T, tot);
        scan_tot<<<1, 256, 0, stream>>>(tot, bstart);
        scatter_kernel<<<NSB, 256, 0, stream>>>(src, dst, r, r_hat, W, b,
                                                baseRel_T, bstart,
                                                packedA, c0a, c1a, c2a);
        const __hip_bfloat16* cpl[3] = { c0a, c1a, c2a };
        for (int i = 0; i < 3; ++i) {
            uv_kernel<<<nblk, 256, 0, stream>>>(
                (const float4*)z, Scum, W + 12 * i, ubuf, vbuf);
            layer_kernel<<<K_BUCKETS, 1024, 0, stream>>>(
                packedA, cpl[i], bstart, ubuf, vbuf, Scum,
                (i == 2) ? 1 : 0, (const float4*)z, (float4*)out);
        }
    } else {
        // -------- fallback: round-2 path --------
        float* agg   = (float*)d_ws;
        float* z_cur = agg + N_NODES;
        dim3 eblk((N_EDGES + 255) / 256);
        init_kernel<<<nblk, 256, 0, stream>>>(
            (const float4*)z, (float4*)z_cur,
            (float4*)(out + 4 * (size_t)N_NODES), agg);
        for (int i = 0; i < 3; ++i) {
            edge_kernel<<<eblk, 256, 0, stream>>>(
                z_cur, r, r_hat, src, dst, W + 12 * i, b + i, agg);
            if (i < 2)
                node_update<<<nblk, 256, 0, stream>>>((float4*)z_cur, agg);
            else
                final_update<<<nblk, 256, 0, stream>>>(
                    (const float4*)z_cur, agg, (float4*)out);
        }
    }
}